// Round 3
// baseline (146.789 us; speedup 1.0000x reference)
//
#include <hip/hip_runtime.h>
#include <hip/hip_bf16.h>
#include <stdint.h>

// Problem constants
#define BATCH 256
#define NPOS 49
#define CCH 128
#define KWIN 7
#define HEADS 4
#define K2 49
#define HD 32
#define MROWS (BATCH * NPOS)         // 12544
#define QSCALE 0.17677669529663687f  // 32^-0.5

// ---------------------------------------------------------------------------
// Register-tiled fp32 GEMM: C[M x N] = A[M x 128] @ W^T + bias
// MODE 0: A=x, N=832 (13 tiles of 64): cols 0..383 -> qkv_buf (q scaled),
//         cols 384..775 -> off_buf, cols 776..831 discarded.
// MODE 1: A=attn_out, N=128 (2 tiles), W0=w_proj -> out + b_proj.
// Per block: 64x64 tile, 256 threads, 4x4 register tile each.
// LDS: As/Bs both [64][128] with XOR swizzle slot = kq ^ (row&7)  (64 KB).
// ---------------------------------------------------------------------------
template <int MODE>
__global__ __launch_bounds__(256) void dwa_gemm(
    const float* __restrict__ A, const float* __restrict__ W0,
    const float* __restrict__ W1, const float* __restrict__ bias0,
    const float* __restrict__ bias1, float* __restrict__ out0,
    float* __restrict__ out1) {
  __shared__ float As[64][128];
  __shared__ float Bs[64][128];
  const int tid = threadIdx.x;
  const int m0 = blockIdx.x * 64;
  const int n0 = blockIdx.y * 64;

  // ---- stage A (rows m0..m0+63, K=128), swizzled ----
  {
    const float4* src = (const float4*)(A + (size_t)m0 * 128);
#pragma unroll
    for (int p = 0; p < 8; ++p) {
      int i4 = tid + p * 256;
      int m = i4 >> 5;
      int kq = i4 & 31;
      float4 v = src[i4];
      int slot = kq ^ (m & 7);
      *(float4*)&As[m][slot << 2] = v;
    }
  }
  // ---- stage B (cols n0..n0+63 of W, i.e. rows of W0/W1), swizzled ----
  {
#pragma unroll
    for (int p = 0; p < 8; ++p) {
      int i4 = tid + p * 256;
      int c = i4 >> 5;
      int kq = i4 & 31;
      int col = n0 + c;
      float4 v;
      if (MODE == 0) {
        if (col < 384)
          v = *(const float4*)&W0[col * 128 + (kq << 2)];
        else if (col < 776)
          v = *(const float4*)&W1[(col - 384) * 128 + (kq << 2)];
        else
          v = make_float4(0.f, 0.f, 0.f, 0.f);
      } else {
        v = *(const float4*)&W0[col * 128 + (kq << 2)];
      }
      int slot = kq ^ (c & 7);
      *(float4*)&Bs[c][slot << 2] = v;
    }
  }
  __syncthreads();

  const int tx = tid & 15;
  const int ty = tid >> 4;
  float acc[4][4];
#pragma unroll
  for (int i = 0; i < 4; ++i)
#pragma unroll
    for (int j = 0; j < 4; ++j) acc[i][j] = 0.f;

#pragma unroll 2
  for (int kq = 0; kq < 32; ++kq) {
    float4 a[4];
#pragma unroll
    for (int i = 0; i < 4; ++i) {
      int m = ty * 4 + i;
      a[i] = *(float4*)&As[m][((kq ^ (m & 7)) << 2)];
    }
    int bslot = (kq ^ (tx & 7)) << 2;
    float4 b0 = *(float4*)&Bs[tx][bslot];
    float4 b1 = *(float4*)&Bs[tx + 16][bslot];
    float4 b2 = *(float4*)&Bs[tx + 32][bslot];
    float4 b3 = *(float4*)&Bs[tx + 48][bslot];
#pragma unroll
    for (int i = 0; i < 4; ++i) {
      acc[i][0] = fmaf(a[i].x, b0.x, acc[i][0]);
      acc[i][0] = fmaf(a[i].y, b0.y, acc[i][0]);
      acc[i][0] = fmaf(a[i].z, b0.z, acc[i][0]);
      acc[i][0] = fmaf(a[i].w, b0.w, acc[i][0]);
      acc[i][1] = fmaf(a[i].x, b1.x, acc[i][1]);
      acc[i][1] = fmaf(a[i].y, b1.y, acc[i][1]);
      acc[i][1] = fmaf(a[i].z, b1.z, acc[i][1]);
      acc[i][1] = fmaf(a[i].w, b1.w, acc[i][1]);
      acc[i][2] = fmaf(a[i].x, b2.x, acc[i][2]);
      acc[i][2] = fmaf(a[i].y, b2.y, acc[i][2]);
      acc[i][2] = fmaf(a[i].z, b2.z, acc[i][2]);
      acc[i][2] = fmaf(a[i].w, b2.w, acc[i][2]);
      acc[i][3] = fmaf(a[i].x, b3.x, acc[i][3]);
      acc[i][3] = fmaf(a[i].y, b3.y, acc[i][3]);
      acc[i][3] = fmaf(a[i].z, b3.z, acc[i][3]);
      acc[i][3] = fmaf(a[i].w, b3.w, acc[i][3]);
    }
  }

  // ---- epilogue ----
  if (MODE == 1) {
    float bj[4];
#pragma unroll
    for (int j = 0; j < 4; ++j) bj[j] = bias0[n0 + tx + 16 * j];
#pragma unroll
    for (int i = 0; i < 4; ++i) {
      float* orow = out0 + (size_t)(m0 + ty * 4 + i) * 128;
#pragma unroll
      for (int j = 0; j < 4; ++j) orow[n0 + tx + 16 * j] = acc[i][j] + bj[j];
    }
  } else {
    if (n0 < 384) {
      const float sc = (n0 < 128) ? QSCALE : 1.0f;
      float bj[4];
#pragma unroll
      for (int j = 0; j < 4; ++j) bj[j] = bias0[n0 + tx + 16 * j];
#pragma unroll
      for (int i = 0; i < 4; ++i) {
        float* orow = out0 + (size_t)(m0 + ty * 4 + i) * 384;
#pragma unroll
        for (int j = 0; j < 4; ++j)
          orow[n0 + tx + 16 * j] = (acc[i][j] + bj[j]) * sc;
      }
    } else {
      float bj[4];
      int oc[4];
      bool ok[4];
#pragma unroll
      for (int j = 0; j < 4; ++j) {
        oc[j] = n0 + tx + 16 * j - 384;
        ok[j] = oc[j] < 392;
        bj[j] = ok[j] ? bias1[oc[j]] : 0.f;
      }
#pragma unroll
      for (int i = 0; i < 4; ++i) {
        float* orow = out1 + (size_t)(m0 + ty * 4 + i) * 392;
#pragma unroll
        for (int j = 0; j < 4; ++j)
          if (ok[j]) orow[oc[j]] = acc[i][j] + bj[j];
      }
    }
  }
}

// ---------------------------------------------------------------------------
// Deformable window attention, one block per (b, h), 256 threads = 4 waves.
// stage q/k/v -> S0 = q@k^T (49x49, register-tiled) -> per-WAVE row loop:
//   lane = k2; coords once; gather S0; wave softmax (shfl_xor); reuse S0 row
//   as A2 row (zero + 4 LDS atomic adds) -- no barriers inside the loop
// -> out = A2 @ v.
// LDS ~33 KB -> 4 blocks/CU.
// ---------------------------------------------------------------------------
__global__ __launch_bounds__(256) void dwa_attn(
    const float* __restrict__ qkv_buf, const float* __restrict__ off_buf,
    const float* __restrict__ rpb, float* __restrict__ attn_out) {
  __shared__ float qs[49][36];    // q rows (pitch 36)
  __shared__ float kt[32][68];    // k transposed: kt[d][n]
  __shared__ float vsh[49][36];   // v rows
  __shared__ float S0A2[49][52];  // S0, reused row-by-row as A2

  const int bh = blockIdx.x;
  const int b = bh >> 2;
  const int h = bh & 3;
  const int tid = threadIdx.x;
  const int lane = tid & 63;
  const int wv = tid >> 6;

  // ---- stage q/k/v ----
  {
    const float* base = qkv_buf + (size_t)(b * 49) * 384 + h * 32;
    for (int i4 = tid; i4 < 392; i4 += 256) {
      int n = i4 >> 3;
      int d4 = (i4 & 7) << 2;
      const float* rowp = base + n * 384 + d4;
      float4 qv = *(const float4*)(rowp);
      float4 kv = *(const float4*)(rowp + 128);
      float4 vv = *(const float4*)(rowp + 256);
      *(float4*)&qs[n][d4] = qv;
      *(float4*)&vsh[n][d4] = vv;
      kt[d4 + 0][n] = kv.x;
      kt[d4 + 1][n] = kv.y;
      kt[d4 + 2][n] = kv.z;
      kt[d4 + 3][n] = kv.w;
    }
  }
  // per-lane constants (k2 = lane)
  const int k2 = lane;
  const int ky = k2 / 7;
  const int kx = k2 - ky * 7;
  float bias = 0.f;
  if (lane < 49) bias = rpb[h * 169 + (ky + 3) * 13 + (kx + 3)];
  __syncthreads();

  // ---- S0 = q @ k^T (49x49, padded compute to 64x64) ----
  {
    const int tx = tid & 15;
    const int ty = tid >> 4;
    int nrow[4];
#pragma unroll
    for (int i = 0; i < 4; ++i) nrow[i] = min(ty * 4 + i, 48);
    float sacc[4][4];
#pragma unroll
    for (int i = 0; i < 4; ++i)
#pragma unroll
      for (int j = 0; j < 4; ++j) sacc[i][j] = 0.f;
#pragma unroll
    for (int kq = 0; kq < 8; ++kq) {
      float4 a[4];
#pragma unroll
      for (int i = 0; i < 4; ++i) a[i] = *(float4*)&qs[nrow[i]][kq << 2];
      float4 bm[4];
#pragma unroll
      for (int u = 0; u < 4; ++u)
        bm[u] = *(float4*)&kt[(kq << 2) + u][tx << 2];
#pragma unroll
      for (int i = 0; i < 4; ++i) {
#pragma unroll
        for (int u = 0; u < 4; ++u) {
          sacc[i][0] = fmaf((&a[i].x)[u], bm[u].x, sacc[i][0]);
          sacc[i][1] = fmaf((&a[i].x)[u], bm[u].y, sacc[i][1]);
          sacc[i][2] = fmaf((&a[i].x)[u], bm[u].z, sacc[i][2]);
          sacc[i][3] = fmaf((&a[i].x)[u], bm[u].w, sacc[i][3]);
        }
      }
    }
    if ((tx << 2) < 49) {  // cols 52..63 never read; row dups benign
#pragma unroll
      for (int i = 0; i < 4; ++i) {
        *(float4*)&S0A2[nrow[i]][tx << 2] =
            make_float4(sacc[i][0], sacc[i][1], sacc[i][2], sacc[i][3]);
      }
    }
  }
  __syncthreads();

  // ---- per-wave row loop: scores + softmax + A2 scatter, no barriers ----
  const float* offp = off_buf + (size_t)(b * 49) * 392 + h * 98;
  for (int n = wv; n < 49; n += 4) {
    unsigned int nu = n;
    int iy = nu / 7u;
    int ix = n - iy * 7;
    float s = -1e30f;
    float pw[4];
    int ii[4];
    if (lane < 49) {
      float2 off2 = *(const float2*)(offp + (size_t)n * 392 + k2 * 2);
      float py = (float)(iy + ky - 3) + off2.x;
      float px = (float)(ix + kx - 3) + off2.y;
      py = fminf(fmaxf(py, 0.f), 6.f);
      px = fminf(fmaxf(px, 0.f), 6.f);
      float y0f = floorf(py), x0f = floorf(px);
      float wy = py - y0f, wx = px - x0f;
      int y0 = (int)y0f, x0 = (int)x0f;
      int y1 = min(y0 + 1, 6), x1 = min(x0 + 1, 6);
      ii[0] = y0 * 7 + x0;
      ii[1] = y0 * 7 + x1;
      ii[2] = y1 * 7 + x0;
      ii[3] = y1 * 7 + x1;
      pw[0] = (1.f - wy) * (1.f - wx);
      pw[1] = (1.f - wy) * wx;
      pw[2] = wy * (1.f - wx);
      pw[3] = wy * wx;
      s = pw[0] * S0A2[n][ii[0]] + pw[1] * S0A2[n][ii[1]] +
          pw[2] * S0A2[n][ii[2]] + pw[3] * S0A2[n][ii[3]] + bias;
    }
    // wave-parallel softmax over 64 lanes (49 valid)
    float mx = s;
#pragma unroll
    for (int d = 32; d; d >>= 1) mx = fmaxf(mx, __shfl_xor(mx, d));
    float p = (lane < 49) ? __expf(s - mx) : 0.f;
    float sum = p;
#pragma unroll
    for (int d = 32; d; d >>= 1) sum += __shfl_xor(sum, d);
    p *= 1.f / sum;
    // reuse S0 row n as A2 row n: all S0 reads for this row are complete
    // (wave-lockstep, in-order DS pipe). Zero then scatter.
    if (lane < 52) S0A2[n][lane] = 0.f;
    if (lane < 49) {
      atomicAdd(&S0A2[n][ii[0]], p * pw[0]);
      atomicAdd(&S0A2[n][ii[1]], p * pw[1]);
      atomicAdd(&S0A2[n][ii[2]], p * pw[2]);
      atomicAdd(&S0A2[n][ii[3]], p * pw[3]);
    }
  }
  __syncthreads();

  // ---- out = A2 @ v ----
  for (int i = tid; i < 1568; i += 256) {
    int n = i >> 5;
    int d = i & 31;
    float acc = 0.f;
#pragma unroll
    for (int m0 = 0; m0 < 48; m0 += 4) {
      float4 a4 = *(float4*)&S0A2[n][m0];
      acc = fmaf(a4.x, vsh[m0 + 0][d], acc);
      acc = fmaf(a4.y, vsh[m0 + 1][d], acc);
      acc = fmaf(a4.z, vsh[m0 + 2][d], acc);
      acc = fmaf(a4.w, vsh[m0 + 3][d], acc);
    }
    acc = fmaf(S0A2[n][48], vsh[48][d], acc);
    attn_out[(size_t)(b * 49 + n) * 128 + h * 32 + d] = acc;
  }
}

// ---------------------------------------------------------------------------
extern "C" void kernel_launch(void* const* d_in, const int* in_sizes, int n_in,
                              void* d_out, int out_size, void* d_ws,
                              size_t ws_size, hipStream_t stream) {
  const float* x = (const float*)d_in[0];
  const float* w_qkv = (const float*)d_in[1];
  const float* b_qkv = (const float*)d_in[2];
  const float* w_off = (const float*)d_in[3];
  const float* b_off = (const float*)d_in[4];
  const float* rpb = (const float*)d_in[5];
  const float* w_proj = (const float*)d_in[6];
  const float* b_proj = (const float*)d_in[7];
  float* out = (float*)d_out;

  float* ws = (float*)d_ws;
  float* qkv_buf = ws;                              // 12544*384
  float* off_buf = qkv_buf + (size_t)MROWS * 384;   // 12544*392
  float* attn_out = off_buf + (size_t)MROWS * 392;  // 12544*128

  dwa_gemm<0><<<dim3(196, 13), 256, 0, stream>>>(x, w_qkv, w_off, b_qkv, b_off,
                                                 qkv_buf, off_buf);
  dwa_attn<<<BATCH * HEADS, 256, 0, stream>>>(qkv_buf, off_buf, rpb, attn_out);
  dwa_gemm<1><<<dim3(196, 2), 256, 0, stream>>>(attn_out, w_proj, nullptr,
                                                b_proj, nullptr, out, nullptr);
}

// Round 4
// 110.679 us; speedup vs baseline: 1.3263x; 1.3263x over previous
//
#include <hip/hip_runtime.h>
#include <hip/hip_bf16.h>
#include <stdint.h>

// Problem constants
#define BATCH 256
#define NPOS 49
#define CCH 128
#define KWIN 7
#define HEADS 4
#define K2 49
#define HD 32
#define MROWS (BATCH * NPOS)         // 12544
#define QSCALE 0.17677669529663687f  // 32^-0.5

using short8 = __attribute__((ext_vector_type(8))) short;
using floatx4 = __attribute__((ext_vector_type(4))) float;

static __device__ inline short f2bf(float x) {
  uint32_t u = __float_as_uint(x);
  uint32_t r = (u + 0x7fffu + ((u >> 16) & 1u)) >> 16;
  return (short)r;
}

// ---------------------------------------------------------------------------
// bf16 MFMA GEMM: C[M x N] = A[M x 128] @ W^T + bias  (A, W fp32 in HBM,
// converted to bf16 during LDS staging; accumulate fp32 in MFMA).
// MODE 0: A=x, N=832 (13 tiles of 64): cols 0..383 -> qkv_buf (q scaled),
//         384..775 -> off_buf, 776..831 discarded.
// MODE 1: A=attn_out, N=128, W0=w_proj -> out + b_proj.
// Block: 64x64 tile, 256 threads = 4 waves; wave w owns 32x32 quadrant
// (2x2 MFMA 16x16 tiles), K=128 in 4 steps of 32.
// LDS: Abs/Bbs [64][128] bf16 (16 KB each), 16B-slot XOR swizzle
// slot' = slot ^ (row & 7)  -> fragment reads are 2-way (free).
// A/B frags use IDENTICAL per-lane addressing; hardware k-permutation
// cancels between operands. C/D layout: col=lane&15, row=(lane>>4)*4+reg.
// ---------------------------------------------------------------------------
template <int MODE>
__global__ __launch_bounds__(256) void dwa_gemm(
    const float* __restrict__ A, const float* __restrict__ W0,
    const float* __restrict__ W1, const float* __restrict__ bias0,
    const float* __restrict__ bias1, float* __restrict__ out0,
    float* __restrict__ out1) {
  __shared__ short Abs[64][128];
  __shared__ short Bbs[64][128];
  const int tid = threadIdx.x;
  const int m0 = blockIdx.x * 64;
  const int n0 = blockIdx.y * 64;

  // ---- stage A: 1024 chunks of 8 bf16 (16B) ----
#pragma unroll
  for (int p = 0; p < 4; ++p) {
    int c = tid + p * 256;
    int row = c >> 4;
    int slot = c & 15;
    const float* src = A + (size_t)(m0 + row) * 128 + slot * 8;
    float4 f0 = *(const float4*)(src);
    float4 f1 = *(const float4*)(src + 4);
    short8 pk;
    pk[0] = f2bf(f0.x); pk[1] = f2bf(f0.y); pk[2] = f2bf(f0.z); pk[3] = f2bf(f0.w);
    pk[4] = f2bf(f1.x); pk[5] = f2bf(f1.y); pk[6] = f2bf(f1.z); pk[7] = f2bf(f1.w);
    *(short8*)&Abs[row][(slot ^ (row & 7)) * 8] = pk;
  }
  // ---- stage B: rows are output cols (rows of W0/W1) ----
#pragma unroll
  for (int p = 0; p < 4; ++p) {
    int c = tid + p * 256;
    int row = c >> 4;
    int slot = c & 15;
    int colg = n0 + row;
    float4 f0 = make_float4(0.f, 0.f, 0.f, 0.f), f1 = f0;
    if (MODE == 1 || colg < 384) {
      const float* src = W0 + (size_t)colg * 128 + slot * 8;
      f0 = *(const float4*)(src);
      f1 = *(const float4*)(src + 4);
    } else if (colg < 776) {
      const float* src = W1 + (size_t)(colg - 384) * 128 + slot * 8;
      f0 = *(const float4*)(src);
      f1 = *(const float4*)(src + 4);
    }
    short8 pk;
    pk[0] = f2bf(f0.x); pk[1] = f2bf(f0.y); pk[2] = f2bf(f0.z); pk[3] = f2bf(f0.w);
    pk[4] = f2bf(f1.x); pk[5] = f2bf(f1.y); pk[6] = f2bf(f1.z); pk[7] = f2bf(f1.w);
    *(short8*)&Bbs[row][(slot ^ (row & 7)) * 8] = pk;
  }
  __syncthreads();

  const int lane = tid & 63;
  const int wv = tid >> 6;
  const int wrow = (wv >> 1) * 32;
  const int wcol = (wv & 1) * 32;
  const int lr = lane & 15;   // row within 16-tile (A) / col within 16-tile (B)
  const int lg = lane >> 4;   // k-group (holds 8 consecutive k)

  floatx4 acc[2][2];
#pragma unroll
  for (int i = 0; i < 2; ++i)
#pragma unroll
    for (int j = 0; j < 2; ++j) acc[i][j] = {0.f, 0.f, 0.f, 0.f};

#pragma unroll
  for (int ks = 0; ks < 4; ++ks) {
    short8 af[2], bf[2];
#pragma unroll
    for (int i = 0; i < 2; ++i) {
      int r = wrow + i * 16 + lr;
      int slot = (ks * 4 + lg) ^ (r & 7);
      af[i] = *(const short8*)&Abs[r][slot * 8];
    }
#pragma unroll
    for (int j = 0; j < 2; ++j) {
      int r = wcol + j * 16 + lr;
      int slot = (ks * 4 + lg) ^ (r & 7);
      bf[j] = *(const short8*)&Bbs[r][slot * 8];
    }
#pragma unroll
    for (int i = 0; i < 2; ++i)
#pragma unroll
      for (int j = 0; j < 2; ++j)
        acc[i][j] = __builtin_amdgcn_mfma_f32_16x16x32_bf16(af[i], bf[j],
                                                            acc[i][j], 0, 0, 0);
  }

  // ---- epilogue: C/D layout col=lane&15, row=(lane>>4)*4+reg ----
#pragma unroll
  for (int i = 0; i < 2; ++i) {
#pragma unroll
    for (int reg = 0; reg < 4; ++reg) {
      int grow = m0 + wrow + i * 16 + lg * 4 + reg;
#pragma unroll
      for (int j = 0; j < 2; ++j) {
        int gcol = n0 + wcol + j * 16 + lr;
        float v = acc[i][j][reg];
        if (MODE == 1) {
          out0[(size_t)grow * 128 + gcol] = v + bias0[gcol];
        } else {
          if (gcol < 384) {
            float sc = (gcol < 128) ? QSCALE : 1.0f;
            out0[(size_t)grow * 384 + gcol] = (v + bias0[gcol]) * sc;
          } else if (gcol < 776) {
            out1[(size_t)grow * 392 + (gcol - 384)] = v + bias1[gcol - 384];
          }
        }
      }
    }
  }
}

// ---------------------------------------------------------------------------
// Deformable window attention, one block per (b, h), 256 threads (fp32).
// Elementwise-parallel phases (high TLP), barriers between:
//   stage q/kt/v -> S0 = q@k^T (register-tiled) -> scores (e-parallel 2401)
//   -> softmax stats (196 thr, 4-lane shfl groups) || zero A2 (60 thr)
//   -> scatter (e-parallel, cached p * inv) -> out = A2 @ v.
// ---------------------------------------------------------------------------
__global__ __launch_bounds__(256) void dwa_attn(
    const float* __restrict__ qkv_buf, const float* __restrict__ off_buf,
    const float* __restrict__ rpb, float* __restrict__ attn_out) {
  __shared__ float qs[49][36];    // q rows
  __shared__ float kt[32][68];    // k transposed: kt[d][n]
  __shared__ float vsh[49][36];   // v rows
  __shared__ float S0A2[49][52];  // S0, then A2
  __shared__ float pm[49][52];    // scores -> unnormalized exp
  __shared__ float bias_s[49];
  __shared__ float inv_s[52];

  const int bh = blockIdx.x;
  const int b = bh >> 2;
  const int h = bh & 3;
  const int tid = threadIdx.x;

  // ---- stage ----
  {
    const float* base = qkv_buf + (size_t)(b * 49) * 384 + h * 32;
    for (int i4 = tid; i4 < 392; i4 += 256) {
      int n = i4 >> 3;
      int d4 = (i4 & 7) << 2;
      const float* rowp = base + n * 384 + d4;
      float4 qv = *(const float4*)(rowp);
      float4 kv = *(const float4*)(rowp + 128);
      float4 vv = *(const float4*)(rowp + 256);
      *(float4*)&qs[n][d4] = qv;
      *(float4*)&vsh[n][d4] = vv;
      kt[d4 + 0][n] = kv.x;
      kt[d4 + 1][n] = kv.y;
      kt[d4 + 2][n] = kv.z;
      kt[d4 + 3][n] = kv.w;
    }
    if (tid < 49) {
      int k2 = tid;
      int ky = k2 / 7, kx = k2 - ky * 7;
      bias_s[k2] = rpb[h * 169 + (ky + 3) * 13 + (kx + 3)];
    }
  }
  __syncthreads();

  // ---- S0 = q @ k^T (49x49, padded compute to 64x64) ----
  {
    const int tx = tid & 15;
    const int ty = tid >> 4;
    int nrow[4];
#pragma unroll
    for (int i = 0; i < 4; ++i) nrow[i] = min(ty * 4 + i, 48);
    float sacc[4][4];
#pragma unroll
    for (int i = 0; i < 4; ++i)
#pragma unroll
      for (int j = 0; j < 4; ++j) sacc[i][j] = 0.f;
#pragma unroll
    for (int kq = 0; kq < 8; ++kq) {
      float4 a[4];
#pragma unroll
      for (int i = 0; i < 4; ++i) a[i] = *(float4*)&qs[nrow[i]][kq << 2];
      float4 bm[4];
#pragma unroll
      for (int u = 0; u < 4; ++u)
        bm[u] = *(float4*)&kt[(kq << 2) + u][tx << 2];
#pragma unroll
      for (int i = 0; i < 4; ++i) {
#pragma unroll
        for (int u = 0; u < 4; ++u) {
          sacc[i][0] = fmaf((&a[i].x)[u], bm[u].x, sacc[i][0]);
          sacc[i][1] = fmaf((&a[i].x)[u], bm[u].y, sacc[i][1]);
          sacc[i][2] = fmaf((&a[i].x)[u], bm[u].z, sacc[i][2]);
          sacc[i][3] = fmaf((&a[i].x)[u], bm[u].w, sacc[i][3]);
        }
      }
    }
    if ((tx << 2) < 49) {
#pragma unroll
      for (int i = 0; i < 4; ++i) {
        *(float4*)&S0A2[nrow[i]][tx << 2] =
            make_float4(sacc[i][0], sacc[i][1], sacc[i][2], sacc[i][3]);
      }
    }
  }
  __syncthreads();

  // ---- scores: s = sum_c w_c * S0[n][idx_c] + bias ----
  const float* offp = off_buf + (size_t)(b * 49) * 392 + h * 98;
  for (int e = tid; e < 2401; e += 256) {
    unsigned int eu = e;
    int n = eu / 49u;
    int k2 = e - n * 49;
    unsigned int nu = n, ku = k2;
    int iy = nu / 7u, ix = n - iy * 7;
    int ky = ku / 7u, kx = k2 - ky * 7;
    float2 off2 = *(const float2*)(offp + (size_t)n * 392 + k2 * 2);
    float py = (float)(iy + ky - 3) + off2.x;
    float px = (float)(ix + kx - 3) + off2.y;
    py = fminf(fmaxf(py, 0.f), 6.f);
    px = fminf(fmaxf(px, 0.f), 6.f);
    float y0f = floorf(py), x0f = floorf(px);
    float wy = py - y0f, wx = px - x0f;
    int y0 = (int)y0f, x0 = (int)x0f;
    int y1 = min(y0 + 1, 6), x1 = min(x0 + 1, 6);
    int i00 = y0 * 7 + x0, i01 = y0 * 7 + x1;
    int i10 = y1 * 7 + x0, i11 = y1 * 7 + x1;
    float w00 = (1.f - wy) * (1.f - wx);
    float w01 = (1.f - wy) * wx;
    float w10 = wy * (1.f - wx);
    float w11 = wy * wx;
    pm[n][k2] = w00 * S0A2[n][i00] + w01 * S0A2[n][i01] +
                w10 * S0A2[n][i10] + w11 * S0A2[n][i11] + bias_s[k2];
  }
  __syncthreads();

  // ---- softmax stats (threads 0..195, 4-lane groups) || zero A2 ----
  if (tid < 196) {
    int r = tid >> 2;
    int q4 = tid & 3;
    float mx = -1e30f;
    for (int k2 = q4; k2 < 49; k2 += 4) mx = fmaxf(mx, pm[r][k2]);
    mx = fmaxf(mx, __shfl_xor(mx, 1));
    mx = fmaxf(mx, __shfl_xor(mx, 2));
    float sum = 0.f;
    for (int k2 = q4; k2 < 49; k2 += 4) {
      float p = __expf(pm[r][k2] - mx);
      pm[r][k2] = p;
      sum += p;
    }
    sum += __shfl_xor(sum, 1);
    sum += __shfl_xor(sum, 2);
    if (q4 == 0) inv_s[r] = 1.f / sum;
  } else {
    float* a2f = &S0A2[0][0];
    for (int i = tid - 196; i < 49 * 52; i += 60) a2f[i] = 0.f;
  }
  __syncthreads();

  // ---- A2 scatter: A2[n][m] += p * inv * w_c ----
  for (int e = tid; e < 2401; e += 256) {
    unsigned int eu = e;
    int n = eu / 49u;
    int k2 = e - n * 49;
    unsigned int nu = n, ku = k2;
    int iy = nu / 7u, ix = n - iy * 7;
    int ky = ku / 7u, kx = k2 - ky * 7;
    float2 off2 = *(const float2*)(offp + (size_t)n * 392 + k2 * 2);
    float py = (float)(iy + ky - 3) + off2.x;
    float px = (float)(ix + kx - 3) + off2.y;
    py = fminf(fmaxf(py, 0.f), 6.f);
    px = fminf(fmaxf(px, 0.f), 6.f);
    float y0f = floorf(py), x0f = floorf(px);
    float wy = py - y0f, wx = px - x0f;
    int y0 = (int)y0f, x0 = (int)x0f;
    int y1 = min(y0 + 1, 6), x1 = min(x0 + 1, 6);
    int i00 = y0 * 7 + x0, i01 = y0 * 7 + x1;
    int i10 = y1 * 7 + x0, i11 = y1 * 7 + x1;
    float p = pm[n][k2] * inv_s[n];
    atomicAdd(&S0A2[n][i00], p * (1.f - wy) * (1.f - wx));
    atomicAdd(&S0A2[n][i01], p * (1.f - wy) * wx);
    atomicAdd(&S0A2[n][i10], p * wy * (1.f - wx));
    atomicAdd(&S0A2[n][i11], p * wy * wx);
  }
  __syncthreads();

  // ---- out = A2 @ v ----
  for (int i = tid; i < 1568; i += 256) {
    int n = i >> 5;
    int d = i & 31;
    float acc = 0.f;
#pragma unroll
    for (int m0 = 0; m0 < 48; m0 += 4) {
      float4 a4 = *(float4*)&S0A2[n][m0];
      acc = fmaf(a4.x, vsh[m0 + 0][d], acc);
      acc = fmaf(a4.y, vsh[m0 + 1][d], acc);
      acc = fmaf(a4.z, vsh[m0 + 2][d], acc);
      acc = fmaf(a4.w, vsh[m0 + 3][d], acc);
    }
    acc = fmaf(S0A2[n][48], vsh[48][d], acc);
    attn_out[(size_t)(b * 49 + n) * 128 + h * 32 + d] = acc;
  }
}

// ---------------------------------------------------------------------------
extern "C" void kernel_launch(void* const* d_in, const int* in_sizes, int n_in,
                              void* d_out, int out_size, void* d_ws,
                              size_t ws_size, hipStream_t stream) {
  const float* x = (const float*)d_in[0];
  const float* w_qkv = (const float*)d_in[1];
  const float* b_qkv = (const float*)d_in[2];
  const float* w_off = (const float*)d_in[3];
  const float* b_off = (const float*)d_in[4];
  const float* rpb = (const float*)d_in[5];
  const float* w_proj = (const float*)d_in[6];
  const float* b_proj = (const float*)d_in[7];
  float* out = (float*)d_out;

  float* ws = (float*)d_ws;
  float* qkv_buf = ws;                              // 12544*384
  float* off_buf = qkv_buf + (size_t)MROWS * 384;   // 12544*392
  float* attn_out = off_buf + (size_t)MROWS * 392;  // 12544*128

  dwa_gemm<0><<<dim3(196, 13), 256, 0, stream>>>(x, w_qkv, w_off, b_qkv, b_off,
                                                 qkv_buf, off_buf);
  dwa_attn<<<BATCH * HEADS, 256, 0, stream>>>(qkv_buf, off_buf, rpb, attn_out);
  dwa_gemm<1><<<dim3(196, 2), 256, 0, stream>>>(attn_out, w_proj, nullptr,
                                                b_proj, nullptr, out, nullptr);
}